// Round 8
// baseline (134.184 us; speedup 1.0000x reference)
//
#include <hip/hip_runtime.h>
#include <cstddef>
#include <cstdint>

// Problem constants: S=8, N=50000, F=5, DEG=32, D_IN=D_OUT=128
static constexpr int S_    = 8;
static constexpr int N_    = 50000;
static constexpr int F_    = 5;
static constexpr int DEG_  = 32;
static constexpr int DOUT_ = 128;
static constexpr int TOTAL_NODES = S_ * N_;            // 400000
static constexpr int NPW = 64;                         // nodes per wave (1/lane)
static constexpr int NWAVES_T = TOTAL_NODES / NPW;     // 6250 (exact)

typedef float f32x4 __attribute__((ext_vector_type(4)));
typedef int   i32x2 __attribute__((ext_vector_type(2)));
typedef int   i32x4 __attribute__((ext_vector_type(4)));

// ---------------------------------------------------------------------------
// Kernel 1: fuse W_1 [5][128] with W [256][128] into Wc [2][5][128].
// ---------------------------------------------------------------------------
__global__ void wc_precompute(const float* __restrict__ W1,
                              const float* __restrict__ W,
                              float* __restrict__ Wc) {
    int t = blockIdx.x * blockDim.x + threadIdx.x;
    if (t >= 2 * F_ * DOUT_) return;
    int o = t & (DOUT_ - 1);
    int f = (t >> 7) % F_;
    int p = t / (F_ * DOUT_);
    const float* w1r  = W1 + f * 128;
    const float* wcol = W + (size_t)p * 128 * DOUT_ + o;
    float acc = 0.f;
#pragma unroll 8
    for (int d = 0; d < 128; ++d)
        acc = fmaf(w1r[d], wcol[(size_t)d * DOUT_], acc);
    Wc[t] = acc;
}

// ---------------------------------------------------------------------------
// Kernel 2: pack x rows into 8B fp8-e4m3 rows (gather table, 3.2 MB, L2-fit).
// ---------------------------------------------------------------------------
__global__ __launch_bounds__(256) void xpack_fp8(const float* __restrict__ x,
                                                 i32x2* __restrict__ xq) {
    int t = blockIdx.x * blockDim.x + threadIdx.x;
    if (t >= TOTAL_NODES) return;
    const float* r = x + (size_t)t * F_;
    int d0 = __builtin_amdgcn_cvt_pk_fp8_f32(r[0], r[1], 0, false);
    d0     = __builtin_amdgcn_cvt_pk_fp8_f32(r[2], r[3], d0, true);
    int d1 = __builtin_amdgcn_cvt_pk_fp8_f32(r[4], 0.f, 0, false);
    i32x2 v; v.x = d0; v.y = d1;
    xq[t] = v;
}

// ---------------------------------------------------------------------------
// Kernel 3: encoder v8 — lane-per-node serial reduction.
//   Phase A: lane <-> node base+lane. 8 coalesced dwordx4 idx loads, then 32
//            independent 8B fp8 gathers accumulated in fp32 (no shuffles).
//            Sums -> LDS at stride 5 (5 coprime 32 -> conflict-free).
//   Phase B: 2 nodes/iter via wave halves; exact fp32 self features; MLP with
//            1/DEG folded into neighbor weights; relu; nt dwordx4 store.
//   Block = 128 (2 waves), grid = 3125 -> exactly 6250 waves, no guard.
// ---------------------------------------------------------------------------
__global__ __launch_bounds__(128) void encoder_v8(
    const int*   __restrict__ idx,   // [S][N][32]
    const i32x2* __restrict__ xq,    // [S*N] fp8 rows (L2-hot)
    const float* __restrict__ x,     // [S][N][5] fp32 (self, exact)
    const float* __restrict__ Wc,    // [2][5][128]
    const float* __restrict__ b,     // [128]
    float* __restrict__ out) {       // [S][N][128]
    __shared__ float lds_sum[2][NPW * F_];   // 2 waves x 320 f32 = 2.5 KB
    const int wv   = threadIdx.x >> 6;
    const int lane = threadIdx.x & 63;
    const int g    = blockIdx.x * 2 + wv;    // 0..6249 (exact)
    const int base = g * NPW;

    // ---- Phase A: per-lane neighbor reduction ----
    {
        const int node = base + lane;
        const int s    = node / N_;          // per-lane (waves may straddle samples)
        const i32x2* __restrict__ xs  = xq + (size_t)s * N_;
        const int*   __restrict__ irow = idx + (size_t)node * DEG_;

        i32x4 nbv[8];                        // all 32 neighbor ids, 8x dwordx4
#pragma unroll
        for (int t = 0; t < 8; ++t)
            nbv[t] = __builtin_nontemporal_load(
                         reinterpret_cast<const i32x4*>(irow) + t);

        float a0 = 0.f, a1 = 0.f, a2 = 0.f, a3 = 0.f, a4 = 0.f;
#pragma unroll
        for (int c = 0; c < 4; ++c) {        // 4 chunks x 8 gathers in flight
            i32x2 q[8];
#pragma unroll
            for (int u = 0; u < 8; ++u) {
                const int k = c * 8 + u;     // compile-time after unroll
                q[u] = xs[nbv[k >> 2][k & 3]];
            }
#pragma unroll
            for (int u = 0; u < 8; ++u) {
                const int d0 = q[u].x, d1 = q[u].y;
                a0 += __builtin_amdgcn_cvt_f32_fp8(d0, 0);
                a1 += __builtin_amdgcn_cvt_f32_fp8(d0, 1);
                a2 += __builtin_amdgcn_cvt_f32_fp8(d0, 2);
                a3 += __builtin_amdgcn_cvt_f32_fp8(d0, 3);
                a4 += __builtin_amdgcn_cvt_f32_fp8(d1, 0);
            }
        }
        float* ls = &lds_sum[wv][lane * F_]; // stride 5: conflict-free writes
        ls[0] = a0; ls[1] = a1; ls[2] = a2; ls[3] = a3; ls[4] = a4;
    }
    __syncthreads();                         // uniform (exact grid, no guard)

    // ---- Phase B: MLP + relu + store ----
    const int sl   = lane & 31;
    const int half = lane >> 5;
    const int o0   = sl << 2;
    const float inv = 1.f / DEG_;

    float wa[F_][4], wb[F_][4];
#pragma unroll
    for (int f = 0; f < F_; ++f) {
        f32x4 a  = *reinterpret_cast<const f32x4*>(Wc + f * DOUT_ + o0);
        f32x4 bb = *reinterpret_cast<const f32x4*>(Wc + F_ * DOUT_ + f * DOUT_ + o0);
        wa[f][0] = a.x;        wa[f][1] = a.y;
        wa[f][2] = a.z;        wa[f][3] = a.w;
        wb[f][0] = bb.x * inv; wb[f][1] = bb.y * inv;   // fold mean(1/32)
        wb[f][2] = bb.z * inv; wb[f][3] = bb.w * inv;
    }
    const f32x4 bias = *reinterpret_cast<const f32x4*>(b + o0);

#pragma unroll 4
    for (int i = 0; i < NPW / 2; ++i) {
        const int nloc = 2 * i + half;
        const int node = base + nloc;
        const float* __restrict__ xr = x + (size_t)node * F_;   // broadcast, exact
        const float* __restrict__ ms = &lds_sum[wv][nloc * F_]; // broadcast LDS
        float y0 = bias.x, y1 = bias.y, y2 = bias.z, y3 = bias.w;
#pragma unroll
        for (int f = 0; f < F_; ++f) {
            const float sf = xr[f];
            const float nf = ms[f];
            y0 = fmaf(sf, wa[f][0], y0); y0 = fmaf(nf, wb[f][0], y0);
            y1 = fmaf(sf, wa[f][1], y1); y1 = fmaf(nf, wb[f][1], y1);
            y2 = fmaf(sf, wa[f][2], y2); y2 = fmaf(nf, wb[f][2], y2);
            y3 = fmaf(sf, wa[f][3], y3); y3 = fmaf(nf, wb[f][3], y3);
        }
        f32x4 yv = { fmaxf(y0, 0.f), fmaxf(y1, 0.f),
                     fmaxf(y2, 0.f), fmaxf(y3, 0.f) };
        __builtin_nontemporal_store(yv,
            reinterpret_cast<f32x4*>(out + (size_t)node * DOUT_ + o0));
    }
}

// ---------------------------------------------------------------------------
// Fallback (fp32 fused path, round-1-proven) if ws_size is too small.
// ---------------------------------------------------------------------------
__global__ __launch_bounds__(256) void encoder_f32(
    const float* __restrict__ x, const int* __restrict__ idx,
    const float* __restrict__ Wc, const float* __restrict__ b,
    float* __restrict__ out, int total_pairs) {
    const int lane = threadIdx.x & 63;
    const int sl   = lane & 31;
    const int half = lane >> 5;
    const int o0   = sl << 2;
    const int gwave  = (blockIdx.x * blockDim.x + threadIdx.x) >> 6;
    const int nwaves = (gridDim.x * blockDim.x) >> 6;
    float wa[F_][4], wb[F_][4];
#pragma unroll
    for (int f = 0; f < F_; ++f) {
        f32x4 a  = *reinterpret_cast<const f32x4*>(Wc + f * DOUT_ + o0);
        f32x4 bb = *reinterpret_cast<const f32x4*>(Wc + F_ * DOUT_ + f * DOUT_ + o0);
        wa[f][0] = a.x;  wa[f][1] = a.y;  wa[f][2] = a.z;  wa[f][3] = a.w;
        wb[f][0] = bb.x; wb[f][1] = bb.y; wb[f][2] = bb.z; wb[f][3] = bb.w;
    }
    const f32x4 bias = *reinterpret_cast<const f32x4*>(b + o0);
    for (int p = gwave; p < total_pairs; p += nwaves) {
        const int node = p * 2 + half;
        const int s    = node / N_;
        const int nb = idx[(size_t)node * DEG_ + sl];
        const float* xr = x + ((size_t)s * N_ + nb) * F_;
        float n0 = xr[0], n1 = xr[1], n2 = xr[2], n3 = xr[3], n4 = xr[4];
#pragma unroll
        for (int m = 1; m < 32; m <<= 1) {
            n0 += __shfl_xor(n0, m); n1 += __shfl_xor(n1, m); n2 += __shfl_xor(n2, m);
            n3 += __shfl_xor(n3, m); n4 += __shfl_xor(n4, m);
        }
        const float inv = 1.f / DEG_;
        const float nf[F_] = {n0 * inv, n1 * inv, n2 * inv, n3 * inv, n4 * inv};
        const float* xsp = x + (size_t)node * F_;
        const float sf[F_] = {xsp[0], xsp[1], xsp[2], xsp[3], xsp[4]};
        float y0 = bias.x, y1 = bias.y, y2 = bias.z, y3 = bias.w;
#pragma unroll
        for (int f = 0; f < F_; ++f) {
            y0 = fmaf(sf[f], wa[f][0], y0); y0 = fmaf(nf[f], wb[f][0], y0);
            y1 = fmaf(sf[f], wa[f][1], y1); y1 = fmaf(nf[f], wb[f][1], y1);
            y2 = fmaf(sf[f], wa[f][2], y2); y2 = fmaf(nf[f], wb[f][2], y2);
            y3 = fmaf(sf[f], wa[f][3], y3); y3 = fmaf(nf[f], wb[f][3], y3);
        }
        f32x4 yv = { fmaxf(y0, 0.f), fmaxf(y1, 0.f), fmaxf(y2, 0.f), fmaxf(y3, 0.f) };
        *reinterpret_cast<f32x4*>(out + (size_t)node * DOUT_ + o0) = yv;
    }
}

extern "C" void kernel_launch(void* const* d_in, const int* in_sizes, int n_in,
                              void* d_out, int out_size, void* d_ws, size_t ws_size,
                              hipStream_t stream) {
    const float* x   = (const float*)d_in[0];
    const int*   idx = (const int*)  d_in[1];
    const float* W1  = (const float*)d_in[2];
    const float* W   = (const float*)d_in[3];
    const float* b   = (const float*)d_in[4];
    float* out = (float*)d_out;

    const size_t wc_bytes = (size_t)2 * F_ * DOUT_ * sizeof(float);  // 5120
    const size_t xq_bytes = (size_t)TOTAL_NODES * sizeof(i32x2);     // 3.2 MB
    float* Wc = (float*)d_ws;

    hipLaunchKernelGGL(wc_precompute, dim3(5), dim3(256), 0, stream, W1, W, Wc);

    if (ws_size >= wc_bytes + xq_bytes) {
        i32x2* xq = (i32x2*)((char*)d_ws + wc_bytes);   // 5120 % 8 == 0
        hipLaunchKernelGGL(xpack_fp8, dim3((TOTAL_NODES + 255) / 256), dim3(256),
                           0, stream, x, xq);
        // 6250 waves exact: 3125 blocks x 128 threads (2 waves/block).
        hipLaunchKernelGGL(encoder_v8, dim3(NWAVES_T / 2), dim3(128), 0, stream,
                           idx, xq, x, Wc, b, out);
    } else {
        hipLaunchKernelGGL(encoder_f32, dim3(2048), dim3(256), 0, stream,
                           x, idx, Wc, b, out, TOTAL_NODES / 2);
    }
}

// Round 9
// 119.465 us; speedup vs baseline: 1.1232x; 1.1232x over previous
//
#include <hip/hip_runtime.h>
#include <cstddef>
#include <cstdint>

// Problem constants: S=8, N=50000, F=5, DEG=32, D_IN=D_OUT=128
static constexpr int S_    = 8;
static constexpr int N_    = 50000;
static constexpr int F_    = 5;
static constexpr int DEG_  = 32;
static constexpr int DOUT_ = 128;
static constexpr int TOTAL_NODES = S_ * N_;              // 400000
static constexpr int NPW = 32;                           // nodes per wave
static constexpr int NCH = NPW / 2;                      // 16 chains (x 2 halves)
static constexpr int TOTAL_WAVES = TOTAL_NODES / NPW;    // 12500 (exact)

typedef float    f32x4 __attribute__((ext_vector_type(4)));
typedef int      i32x2 __attribute__((ext_vector_type(2)));
typedef int      i32x4 __attribute__((ext_vector_type(4)));
typedef _Float16 h2    __attribute__((ext_vector_type(2)));

// DPP row-rotate + packed-f16 add. ROW_ROR:n = 0x120|n; rotations {1,2,4,8}
// within each 16-lane row give every lane the full row sum (classic
// rotate-reduce; permutation-invariant, same log-depth as xor butterfly).
#define ROR_ADD(v, CTRL)                                                      \
    { int t_ = __builtin_amdgcn_update_dpp(                                   \
          0, __builtin_bit_cast(int, v), (CTRL), 0xF, 0xF, true);             \
      v += __builtin_bit_cast(h2, t_); }

// ---------------------------------------------------------------------------
// Kernel 1: fuse W_1 [5][128] with W [256][128] into Wc [2][5][128].
// ---------------------------------------------------------------------------
__global__ void wc_precompute(const float* __restrict__ W1,
                              const float* __restrict__ W,
                              float* __restrict__ Wc) {
    int t = blockIdx.x * blockDim.x + threadIdx.x;
    if (t >= 2 * F_ * DOUT_) return;
    int o = t & (DOUT_ - 1);
    int f = (t >> 7) % F_;
    int p = t / (F_ * DOUT_);
    const float* w1r  = W1 + f * 128;
    const float* wcol = W + (size_t)p * 128 * DOUT_ + o;
    float acc = 0.f;
#pragma unroll 8
    for (int d = 0; d < 128; ++d)
        acc = fmaf(w1r[d], wcol[(size_t)d * DOUT_], acc);
    Wc[t] = acc;
}

// ---------------------------------------------------------------------------
// Kernel 2: ONE pass over x -> both tables: 8B fp8 rows (gather, 3.2 MB,
// L2-fit) and 16B f16 rows (self, coalesced broadcast reads).
// ---------------------------------------------------------------------------
struct alignas(16) H8 { _Float16 v[8]; };

__global__ __launch_bounds__(256) void xpack_both(const float* __restrict__ x,
                                                  i32x2* __restrict__ xq,
                                                  H8* __restrict__ xh) {
    int t = blockIdx.x * blockDim.x + threadIdx.x;
    if (t >= TOTAL_NODES) return;
    const float* r = x + (size_t)t * F_;
    const float r0 = r[0], r1 = r[1], r2 = r[2], r3 = r[3], r4 = r[4];
    int d0 = __builtin_amdgcn_cvt_pk_fp8_f32(r0, r1, 0, false);
    d0     = __builtin_amdgcn_cvt_pk_fp8_f32(r2, r3, d0, true);
    int d1 = __builtin_amdgcn_cvt_pk_fp8_f32(r4, 0.f, 0, false);
    i32x2 q; q.x = d0; q.y = d1;
    xq[t] = q;
    H8 o;
    o.v[0] = (_Float16)r0; o.v[1] = (_Float16)r1; o.v[2] = (_Float16)r2;
    o.v[3] = (_Float16)r3; o.v[4] = (_Float16)r4;
    o.v[5] = (_Float16)0.f; o.v[6] = (_Float16)0.f; o.v[7] = (_Float16)0.f;
    xh[t] = o;
}

// ---------------------------------------------------------------------------
// Kernel 3: encoder v9. One wave = 32 nodes (16 chains x 2 halves).
//   All 16 idx loads + all 16 gathers issued up front (deep MLP); self rows
//   in 4 batches of 4 (bounds VGPR). Reduction: 4x DPP rotate-add within
//   16-lane rows + one shfl_xor(16) per dword (DS ops 15 -> 3 per chain).
//   1/DEG folded into neighbor weights. nt dwordx4 stores (1KB/wave/chain).
// ---------------------------------------------------------------------------
__global__ __launch_bounds__(256) void encoder_v9(
    const int*   __restrict__ idx,   // [S][N][32]
    const i32x2* __restrict__ xq,    // [S*N] fp8 rows (L2-hot)
    const H8*    __restrict__ xh,    // [S*N] f16 rows (self)
    const float* __restrict__ Wc,    // [2][5][128]
    const float* __restrict__ b,     // [128]
    float* __restrict__ out) {       // [S][N][128]
    const int lane = threadIdx.x & 63;
    const int sl   = lane & 31;
    const int half = lane >> 5;
    const int o0   = sl << 2;
    const int w    = (blockIdx.x * blockDim.x + threadIdx.x) >> 6;  // 0..12499
    const int base = w * NPW;

    // Fused weights; fold mean(1/32) into neighbor half.
    const float inv = 1.f / DEG_;
    float wa[F_][4], wb[F_][4];
#pragma unroll
    for (int f = 0; f < F_; ++f) {
        f32x4 a  = *reinterpret_cast<const f32x4*>(Wc + f * DOUT_ + o0);
        f32x4 bb = *reinterpret_cast<const f32x4*>(Wc + F_ * DOUT_ + f * DOUT_ + o0);
        wa[f][0] = a.x;        wa[f][1] = a.y;
        wa[f][2] = a.z;        wa[f][3] = a.w;
        wb[f][0] = bb.x * inv; wb[f][1] = bb.y * inv;
        wb[f][2] = bb.z * inv; wb[f][3] = bb.w * inv;
    }
    const f32x4 bias = *reinterpret_cast<const f32x4*>(b + o0);

    // --- 16 idx loads up front (coalesced 256B per chain) ---
    int nb[NCH];
#pragma unroll
    for (int j = 0; j < NCH; ++j) {
        const int node = base + 2 * j + half;
        nb[j] = __builtin_nontemporal_load(idx + (size_t)node * DEG_ + sl);
    }
    // --- 16 scattered 8B gathers up front (L2-resident table) ---
    i32x2 gq[NCH];
#pragma unroll
    for (int j = 0; j < NCH; ++j) {
        const int s = (base + 2 * j) / N_;   // uniform within chain (pair 2m,2m+1)
        gq[j] = xq[(size_t)s * N_ + nb[j]];
    }

    // --- 4 batches of 4 chains: self loads + reduce + MLP + store ---
#pragma unroll
    for (int bt = 0; bt < 4; ++bt) {
        union US { i32x4 i; h2 h[4]; } sv[4];
#pragma unroll
        for (int u = 0; u < 4; ++u) {
            const int node = base + 2 * (4 * bt + u) + half;
            sv[u].i = *reinterpret_cast<const i32x4*>(xh + node);  // broadcast
        }
#pragma unroll
        for (int u = 0; u < 4; ++u) {
            const int j  = 4 * bt + u;
            const int d0 = gq[j].x, d1 = gq[j].y;
            h2 v0 = { (_Float16)__builtin_amdgcn_cvt_f32_fp8(d0, 0),
                      (_Float16)__builtin_amdgcn_cvt_f32_fp8(d0, 1) };
            h2 v1 = { (_Float16)__builtin_amdgcn_cvt_f32_fp8(d0, 2),
                      (_Float16)__builtin_amdgcn_cvt_f32_fp8(d0, 3) };
            h2 v2 = { (_Float16)__builtin_amdgcn_cvt_f32_fp8(d1, 0),
                      (_Float16)0.f };
            // rotate-reduce within 16-lane rows (VALU, no DS pipe)
            ROR_ADD(v0, 0x121); ROR_ADD(v1, 0x121); ROR_ADD(v2, 0x121);
            ROR_ADD(v0, 0x122); ROR_ADD(v1, 0x122); ROR_ADD(v2, 0x122);
            ROR_ADD(v0, 0x124); ROR_ADD(v1, 0x124); ROR_ADD(v2, 0x124);
            ROR_ADD(v0, 0x128); ROR_ADD(v1, 0x128); ROR_ADD(v2, 0x128);
            // cross-row combine within each 32-lane half (3 DS ops)
            v0 += __builtin_bit_cast(h2, __shfl_xor(__builtin_bit_cast(int, v0), 16));
            v1 += __builtin_bit_cast(h2, __shfl_xor(__builtin_bit_cast(int, v1), 16));
            v2 += __builtin_bit_cast(h2, __shfl_xor(__builtin_bit_cast(int, v2), 16));

            const float nf[F_] = { (float)v0.x, (float)v0.y,
                                   (float)v1.x, (float)v1.y, (float)v2.x };
            const float sf[F_] = { (float)sv[u].h[0].x, (float)sv[u].h[0].y,
                                   (float)sv[u].h[1].x, (float)sv[u].h[1].y,
                                   (float)sv[u].h[2].x };
            float y0 = bias.x, y1 = bias.y, y2 = bias.z, y3 = bias.w;
#pragma unroll
            for (int f = 0; f < F_; ++f) {
                y0 = fmaf(sf[f], wa[f][0], y0); y0 = fmaf(nf[f], wb[f][0], y0);
                y1 = fmaf(sf[f], wa[f][1], y1); y1 = fmaf(nf[f], wb[f][1], y1);
                y2 = fmaf(sf[f], wa[f][2], y2); y2 = fmaf(nf[f], wb[f][2], y2);
                y3 = fmaf(sf[f], wa[f][3], y3); y3 = fmaf(nf[f], wb[f][3], y3);
            }
            const int node = base + 2 * j + half;
            f32x4 yv = { fmaxf(y0, 0.f), fmaxf(y1, 0.f),
                         fmaxf(y2, 0.f), fmaxf(y3, 0.f) };
            __builtin_nontemporal_store(yv,
                reinterpret_cast<f32x4*>(out + (size_t)node * DOUT_ + o0));
        }
    }
}

// ---------------------------------------------------------------------------
// Fallback (fp32 fused path) if ws_size is too small.
// ---------------------------------------------------------------------------
__global__ __launch_bounds__(256) void encoder_f32(
    const float* __restrict__ x, const int* __restrict__ idx,
    const float* __restrict__ Wc, const float* __restrict__ b,
    float* __restrict__ out, int total_pairs) {
    const int lane = threadIdx.x & 63;
    const int sl   = lane & 31;
    const int half = lane >> 5;
    const int o0   = sl << 2;
    const int gwave  = (blockIdx.x * blockDim.x + threadIdx.x) >> 6;
    const int nwaves = (gridDim.x * blockDim.x) >> 6;
    float wa[F_][4], wb[F_][4];
#pragma unroll
    for (int f = 0; f < F_; ++f) {
        f32x4 a  = *reinterpret_cast<const f32x4*>(Wc + f * DOUT_ + o0);
        f32x4 bb = *reinterpret_cast<const f32x4*>(Wc + F_ * DOUT_ + f * DOUT_ + o0);
        wa[f][0] = a.x;  wa[f][1] = a.y;  wa[f][2] = a.z;  wa[f][3] = a.w;
        wb[f][0] = bb.x; wb[f][1] = bb.y; wb[f][2] = bb.z; wb[f][3] = bb.w;
    }
    const f32x4 bias = *reinterpret_cast<const f32x4*>(b + o0);
    for (int p = gwave; p < total_pairs; p += nwaves) {
        const int node = p * 2 + half;
        const int s    = node / N_;
        const int nb = idx[(size_t)node * DEG_ + sl];
        const float* xr = x + ((size_t)s * N_ + nb) * F_;
        float n0 = xr[0], n1 = xr[1], n2 = xr[2], n3 = xr[3], n4 = xr[4];
#pragma unroll
        for (int m = 1; m < 32; m <<= 1) {
            n0 += __shfl_xor(n0, m); n1 += __shfl_xor(n1, m); n2 += __shfl_xor(n2, m);
            n3 += __shfl_xor(n3, m); n4 += __shfl_xor(n4, m);
        }
        const float inv = 1.f / DEG_;
        const float nf[F_] = {n0 * inv, n1 * inv, n2 * inv, n3 * inv, n4 * inv};
        const float* xsp = x + (size_t)node * F_;
        const float sf[F_] = {xsp[0], xsp[1], xsp[2], xsp[3], xsp[4]};
        float y0 = bias.x, y1 = bias.y, y2 = bias.z, y3 = bias.w;
#pragma unroll
        for (int f = 0; f < F_; ++f) {
            y0 = fmaf(sf[f], wa[f][0], y0); y0 = fmaf(nf[f], wb[f][0], y0);
            y1 = fmaf(sf[f], wa[f][1], y1); y1 = fmaf(nf[f], wb[f][1], y1);
            y2 = fmaf(sf[f], wa[f][2], y2); y2 = fmaf(nf[f], wb[f][2], y2);
            y3 = fmaf(sf[f], wa[f][3], y3); y3 = fmaf(nf[f], wb[f][3], y3);
        }
        f32x4 yv = { fmaxf(y0, 0.f), fmaxf(y1, 0.f), fmaxf(y2, 0.f), fmaxf(y3, 0.f) };
        *reinterpret_cast<f32x4*>(out + (size_t)node * DOUT_ + o0) = yv;
    }
}

extern "C" void kernel_launch(void* const* d_in, const int* in_sizes, int n_in,
                              void* d_out, int out_size, void* d_ws, size_t ws_size,
                              hipStream_t stream) {
    const float* x   = (const float*)d_in[0];
    const int*   idx = (const int*)  d_in[1];
    const float* W1  = (const float*)d_in[2];
    const float* W   = (const float*)d_in[3];
    const float* b   = (const float*)d_in[4];
    float* out = (float*)d_out;

    const size_t wc_bytes = (size_t)2 * F_ * DOUT_ * sizeof(float);  // 5120
    const size_t xq_bytes = (size_t)TOTAL_NODES * sizeof(i32x2);     // 3.2 MB
    const size_t xh_bytes = (size_t)TOTAL_NODES * sizeof(H8);        // 6.4 MB
    float* Wc = (float*)d_ws;

    hipLaunchKernelGGL(wc_precompute, dim3(5), dim3(256), 0, stream, W1, W, Wc);

    if (ws_size >= wc_bytes + xq_bytes + xh_bytes) {
        i32x2* xq = (i32x2*)((char*)d_ws + wc_bytes);
        H8*    xh = (H8*)   ((char*)d_ws + wc_bytes + xq_bytes);  // 16B-aligned
        hipLaunchKernelGGL(xpack_both, dim3((TOTAL_NODES + 255) / 256), dim3(256),
                           0, stream, x, xq, xh);
        // Exact dispatch: 12500 waves, 4 waves/block -> 3125 blocks.
        hipLaunchKernelGGL(encoder_v9, dim3(TOTAL_WAVES / 4), dim3(256), 0, stream,
                           idx, xq, xh, Wc, b, out);
    } else {
        hipLaunchKernelGGL(encoder_f32, dim3(2048), dim3(256), 0, stream,
                           x, idx, Wc, b, out, TOTAL_NODES / 2);
    }
}